// Round 11
// baseline (1201.443 us; speedup 1.0000x reference)
//
#include <hip/hip_runtime.h>

#define N_NODES 100000
#define N_EDGES 1600000
#define MPAD    100096   // 782 * 128
#define NB_SCAN ((N_NODES + 255) / 256)   // 391

using short8  = __attribute__((ext_vector_type(8))) short;
using ushort8 = __attribute__((ext_vector_type(8))) unsigned short;
using f32x4   = __attribute__((ext_vector_type(4))) float;

__device__ inline unsigned short f2bf(float f) {
    unsigned u = __float_as_uint(f);
    unsigned r = (u + 0x7fffu + ((u >> 16) & 1u)) >> 16;  // RNE
    return (unsigned short)r;
}
__device__ inline float bf2f(unsigned short h) {
    return __uint_as_float(((unsigned)h) << 16);
}

// ---------------- CSR build (double counting sort: src-major, then dst) ----------------

__global__ __launch_bounds__(256) void k_init(int* __restrict__ scnt,
                                              int* __restrict__ dcnt, int n) {
    int i = blockIdx.x * blockDim.x + threadIdx.x;
    if (i < n) { scnt[i] = 0; dcnt[i] = 0; }
}

__global__ __launch_bounds__(256) void k_hist(const int* __restrict__ src,
                                              const int* __restrict__ dst,
                                              int* __restrict__ scnt,
                                              int* __restrict__ dcnt, int e) {
    int i = (blockIdx.x * blockDim.x + threadIdx.x) * 4;
    if (i < e) {
        int4 s = *(const int4*)(src + i);
        int4 d = *(const int4*)(dst + i);
        atomicAdd(&scnt[s.x], 1); atomicAdd(&scnt[s.y], 1);
        atomicAdd(&scnt[s.z], 1); atomicAdd(&scnt[s.w], 1);
        atomicAdd(&dcnt[d.x], 1); atomicAdd(&dcnt[d.y], 1);
        atomicAdd(&dcnt[d.z], 1); atomicAdd(&dcnt[d.w], 1);
    }
}

__global__ __launch_bounds__(256) void k_scan_blocks(const int* __restrict__ cnt,
                                                     int* __restrict__ blksum, int n) {
    int i = blockIdx.x * 256 + threadIdx.x;
    int v = (i < n) ? cnt[i] : 0;
#pragma unroll
    for (int o = 32; o > 0; o >>= 1) v += __shfl_down(v, o, 64);
    __shared__ int ws[4];
    if ((threadIdx.x & 63) == 0) ws[threadIdx.x >> 6] = v;
    __syncthreads();
    if (threadIdx.x == 0) blksum[blockIdx.x] = ws[0] + ws[1] + ws[2] + ws[3];
}

__global__ __launch_bounds__(512) void k_scan_top(const int* __restrict__ blksum,
                                                  int* __restrict__ blkpref,
                                                  int* __restrict__ offsets, int nb, int n) {
    __shared__ int s[512];
    int t = threadIdx.x;
    int v = (t < nb) ? blksum[t] : 0;
    s[t] = v;
    __syncthreads();
    for (int o = 1; o < 512; o <<= 1) {
        int u = (t >= o) ? s[t - o] : 0;
        __syncthreads();
        s[t] += u;
        __syncthreads();
    }
    if (t < nb) blkpref[t] = (t == 0) ? 0 : s[t - 1];
    if (t == nb - 1) offsets[n] = s[t];
}

// local scan; optionally also emits dinv (pass nullptr for the src pass)
__global__ __launch_bounds__(256) void k_scan_final(const int* __restrict__ cnt,
                                                    const int* __restrict__ blkpref,
                                                    int* __restrict__ offsets,
                                                    float* __restrict__ dinv, int n) {
    __shared__ int s[256];
    int t = threadIdx.x;
    int i = blockIdx.x * 256 + t;
    int v = (i < n) ? cnt[i] : 0;
    s[t] = v;
    __syncthreads();
    for (int o = 1; o < 256; o <<= 1) {
        int u = (t >= o) ? s[t - o] : 0;
        __syncthreads();
        s[t] += u;
        __syncthreads();
    }
    if (i < n) {
        offsets[i] = blkpref[blockIdx.x] + s[t] - v;   // exclusive prefix
        if (dinv) dinv[i] = rsqrtf((float)(v + 1));    // +1 self-loop
    }
}

// pass 1: scatter edges into src-major order; consumes scnt as countdown cursor
__global__ __launch_bounds__(256) void k_scatter1(const int* __restrict__ src,
                                                  const int* __restrict__ dst,
                                                  const int* __restrict__ soff,
                                                  int* __restrict__ scnt,
                                                  int2* __restrict__ tmp, int e) {
    int i = blockIdx.x * blockDim.x + threadIdx.x;
    if (i < e) {
        int s = src[i];
        int p = soff[s] + atomicSub(&scnt[s], 1) - 1;
        tmp[p] = make_int2(s, dst[i]);
    }
}

// pass 2: walk src-sorted list in order; scatter into dst-CSR (approx src-ordered lists)
__global__ __launch_bounds__(256) void k_scatter2(const int2* __restrict__ tmp,
                                                  const int* __restrict__ doff,
                                                  int* __restrict__ dcnt,
                                                  int* __restrict__ csr_src, int e) {
    int p = blockIdx.x * blockDim.x + threadIdx.x;
    if (p < e) {
        int2 sd = tmp[p];
        int pos = doff[sd.y] + atomicSub(&dcnt[sd.y], 1) - 1;
        csr_src[pos] = sd.x;
    }
}

// ---------------- prep: x -> bf16 (padded), W -> W^T bf16 ----------------

__global__ __launch_bounds__(256) void k_cvt_x(const float* __restrict__ x,
                                               unsigned short* __restrict__ xb) {
    int i = blockIdx.x * blockDim.x + threadIdx.x;     // one thread = 4 elems
    int row = i >> 6;
    ushort4 o;
    if (row < N_NODES) {
        float4 v = *(const float4*)(x + (size_t)i * 4);
        o.x = f2bf(v.x); o.y = f2bf(v.y); o.z = f2bf(v.z); o.w = f2bf(v.w);
    } else {
        o.x = o.y = o.z = o.w = 0;
    }
    *(ushort4*)(xb + (size_t)i * 4) = o;
}

// W [K=256][N] f32 -> Wt [N][256] bf16
__global__ __launch_bounds__(256) void k_prep_w(const float* __restrict__ W,
                                                unsigned short* __restrict__ Wt, int N) {
    int i = blockIdx.x * blockDim.x + threadIdx.x;
    if (i < 256 * N) {
        int r = i / N, c = i - r * N;
        Wt[(size_t)c * 256 + r] = f2bf(W[i]);
    }
}

// ---------------- bf16 MFMA GEMM (encoder/conv/decoder): C = [dinv ⊙] (A @ Bt^T) ----------------

template <int BN, bool DSCALE>
__global__ __launch_bounds__(256) void k_mfma_gemm(const unsigned short* __restrict__ A,
                                                   const unsigned short* __restrict__ Bt,
                                                   const float* __restrict__ dinv,
                                                   unsigned short* __restrict__ C,
                                                   int Ntot) {
    constexpr int K = 256, BK = 64;
    constexpr int NFR = BN / 32;            // 16-col frags per wave
    __shared__ char ldsA[128 * 128];
    __shared__ char ldsB[BN * 128];
    const int tid  = threadIdx.x;
    const int lane = tid & 63;
    const int wid  = tid >> 6;
    const int wr   = wid >> 1, wc = wid & 1;
    const int row0 = blockIdx.x * 128;
    const int col0 = blockIdx.y * BN;
    const int l15  = lane & 15, lhi = lane >> 4;

    f32x4 acc[4][NFR];
#pragma unroll
    for (int m = 0; m < 4; ++m)
#pragma unroll
        for (int n = 0; n < NFR; ++n) acc[m][n] = {0.f, 0.f, 0.f, 0.f};

    for (int k0 = 0; k0 < K; k0 += BK) {
#pragma unroll
        for (int j = 0; j < 4; ++j) {
            int ci = j * 256 + tid;
            int r = ci >> 3;
            int cb = (ci & 7) ^ (r & 7);
            const char* src = (const char*)(A + (size_t)(row0 + r) * K + k0) + cb * 16;
            __builtin_amdgcn_global_load_lds((const __attribute__((address_space(1))) void*)src,
                                             (__attribute__((address_space(3))) void*)(ldsA + ci * 16),
                                             16, 0, 0);
        }
#pragma unroll
        for (int j = 0; j < BN / 32; ++j) {
            int ci = j * 256 + tid;
            int r = ci >> 3;
            int cb = (ci & 7) ^ (r & 7);
            const char* src = (const char*)(Bt + (size_t)(col0 + r) * K + k0) + cb * 16;
            __builtin_amdgcn_global_load_lds((const __attribute__((address_space(1))) void*)src,
                                             (__attribute__((address_space(3))) void*)(ldsB + ci * 16),
                                             16, 0, 0);
        }
        __syncthreads();
#pragma unroll
        for (int kk = 0; kk < 2; ++kk) {
            short8 af[4], bfr[NFR];
            int cb = kk * 4 + lhi;
#pragma unroll
            for (int m = 0; m < 4; ++m) {
                int r = wr * 64 + m * 16 + l15;
                af[m] = *(const short8*)(ldsA + r * 128 + ((cb ^ (r & 7)) << 4));
            }
#pragma unroll
            for (int n = 0; n < NFR; ++n) {
                int r = wc * (NFR * 16) + n * 16 + l15;
                bfr[n] = *(const short8*)(ldsB + r * 128 + ((cb ^ (r & 7)) << 4));
            }
#pragma unroll
            for (int m = 0; m < 4; ++m)
#pragma unroll
                for (int n = 0; n < NFR; ++n)
                    acc[m][n] = __builtin_amdgcn_mfma_f32_16x16x32_bf16(af[m], bfr[n],
                                                                        acc[m][n], 0, 0, 0);
        }
        __syncthreads();
    }
#pragma unroll
    for (int m = 0; m < 4; ++m) {
        int rbase = row0 + wr * 64 + m * 16 + lhi * 4;
        float sc[4];
#pragma unroll
        for (int q = 0; q < 4; ++q) {
            int grow = rbase + q;
            sc[q] = DSCALE ? ((grow < N_NODES) ? dinv[grow] : 0.f) : 1.f;
        }
#pragma unroll
        for (int n = 0; n < NFR; ++n) {
            int col = col0 + wc * (NFR * 16) + n * 16 + l15;
#pragma unroll
            for (int q = 0; q < 4; ++q)
                C[(size_t)(rbase + q) * Ntot + col] = f2bf(acc[m][n][q] * sc[q]);
        }
    }
}

// ---------------- aggregation F=256: out = relu(dinv[d]*(sum H'[s] + H'[d]) + b) ----------------
// one wave per node; half-wave per edge (32 lanes x 16B); weightless edges (R7 version).

__global__ __launch_bounds__(256) void k_agg256(const unsigned short* __restrict__ H,
                                                const int* __restrict__ offsets,
                                                const int* __restrict__ csr_src,
                                                const float* __restrict__ dinv,
                                                const float* __restrict__ bias,
                                                unsigned short* __restrict__ out, int n) {
    const int wid = __builtin_amdgcn_readfirstlane((blockIdx.x * blockDim.x + threadIdx.x) >> 6);
    if (wid >= n) return;
    const int lane = threadIdx.x & 63;
    const int half = lane >> 5;
    const unsigned coff = (unsigned)(lane & 31) * 16u;

    float acc[8] = {};
    const int beg = offsets[wid], end = offsets[wid + 1];
    int e = beg;

    for (; e + 7 < end; e += 8) {
        int sj[8];
#pragma unroll
        for (int j = 0; j < 8; ++j) sj[j] = csr_src[e + j];
        unsigned o0 = (unsigned)(half ? sj[1] : sj[0]) * 512u + coff;
        unsigned o1 = (unsigned)(half ? sj[3] : sj[2]) * 512u + coff;
        unsigned o2 = (unsigned)(half ? sj[5] : sj[4]) * 512u + coff;
        unsigned o3 = (unsigned)(half ? sj[7] : sj[6]) * 512u + coff;
        ushort8 v0 = *(const ushort8*)((const char*)H + o0);
        ushort8 v1 = *(const ushort8*)((const char*)H + o1);
        ushort8 v2 = *(const ushort8*)((const char*)H + o2);
        ushort8 v3 = *(const ushort8*)((const char*)H + o3);
#pragma unroll
        for (int j = 0; j < 8; ++j) acc[j] += bf2f(v0[j]);
#pragma unroll
        for (int j = 0; j < 8; ++j) acc[j] += bf2f(v1[j]);
#pragma unroll
        for (int j = 0; j < 8; ++j) acc[j] += bf2f(v2[j]);
#pragma unroll
        for (int j = 0; j < 8; ++j) acc[j] += bf2f(v3[j]);
    }
    for (; e + 1 < end; e += 2) {
        int s0 = csr_src[e], s1 = csr_src[e + 1];
        unsigned off = (unsigned)(half ? s1 : s0) * 512u + coff;
        ushort8 v = *(const ushort8*)((const char*)H + off);
#pragma unroll
        for (int j = 0; j < 8; ++j) acc[j] += bf2f(v[j]);
    }
    // virtual pair: [tail edge (if any), self-loop]
    {
        int has_tail = (e < end);
        int sA = has_tail ? csr_src[e] : wid;
        float wB = has_tail ? 1.f : 0.f;
        unsigned off = (unsigned)(half ? wid : sA) * 512u + coff;
        float w = half ? wB : 1.f;
        ushort8 v = *(const ushort8*)((const char*)H + off);
#pragma unroll
        for (int j = 0; j < 8; ++j) acc[j] = fmaf(bf2f(v[j]), w, acc[j]);
    }

#pragma unroll
    for (int j = 0; j < 8; ++j) acc[j] += __shfl_xor(acc[j], 32);

    if (half == 0) {
        float dv = dinv[wid];
        const float* bp = bias + (lane & 31) * 8;
        float4 b0 = *(const float4*)bp;
        float4 b1 = *(const float4*)(bp + 4);
        ushort8 o;
        o[0] = f2bf(fmaxf(fmaf(acc[0], dv, b0.x), 0.f));
        o[1] = f2bf(fmaxf(fmaf(acc[1], dv, b0.y), 0.f));
        o[2] = f2bf(fmaxf(fmaf(acc[2], dv, b0.z), 0.f));
        o[3] = f2bf(fmaxf(fmaf(acc[3], dv, b0.w), 0.f));
        o[4] = f2bf(fmaxf(fmaf(acc[4], dv, b1.x), 0.f));
        o[5] = f2bf(fmaxf(fmaf(acc[5], dv, b1.y), 0.f));
        o[6] = f2bf(fmaxf(fmaf(acc[6], dv, b1.z), 0.f));
        o[7] = f2bf(fmaxf(fmaf(acc[7], dv, b1.w), 0.f));
        *(ushort8*)((char*)out + (unsigned)wid * 512u + coff) = o;
    }
}

// ---------------- aggregation F=64 (decoder): f32 out ----------------

__global__ __launch_bounds__(256) void k_agg64(const unsigned short* __restrict__ H,
                                               const int* __restrict__ offsets,
                                               const int* __restrict__ csr_src,
                                               const float* __restrict__ dinv,
                                               const float* __restrict__ bias,
                                               float* __restrict__ out, int n) {
    const int wid = __builtin_amdgcn_readfirstlane((blockIdx.x * blockDim.x + threadIdx.x) >> 6);
    if (wid >= n) return;
    const int lane = threadIdx.x & 63;
    const int q = lane >> 4;
    const unsigned coff = (unsigned)(lane & 15) * 8u;

    float acc[4] = {};
    const int beg = offsets[wid], end = offsets[wid + 1];
    int e = beg;

    for (; e + 3 < end; e += 4) {
        int s0 = csr_src[e], s1 = csr_src[e + 1], s2 = csr_src[e + 2], s3 = csr_src[e + 3];
        int srow = s0;
        if (q == 1) srow = s1;
        else if (q == 2) srow = s2;
        else if (q == 3) srow = s3;
        ushort4 v = *(const ushort4*)((const char*)H + (unsigned)srow * 128u + coff);
        acc[0] += bf2f(v.x); acc[1] += bf2f(v.y);
        acc[2] += bf2f(v.z); acc[3] += bf2f(v.w);
    }
    {
        int r = end - e;
        int srow = wid; float wgt = 0.f;
        if (q < r) { srow = csr_src[e + q]; wgt = 1.f; }
        else if (q == r) { srow = wid; wgt = 1.f; }
        ushort4 v = *(const ushort4*)((const char*)H + (unsigned)srow * 128u + coff);
        acc[0] = fmaf(bf2f(v.x), wgt, acc[0]);
        acc[1] = fmaf(bf2f(v.y), wgt, acc[1]);
        acc[2] = fmaf(bf2f(v.z), wgt, acc[2]);
        acc[3] = fmaf(bf2f(v.w), wgt, acc[3]);
    }
#pragma unroll
    for (int j = 0; j < 4; ++j) {
        acc[j] += __shfl_xor(acc[j], 16);
        acc[j] += __shfl_xor(acc[j], 32);
    }
    if (q == 0) {
        float dv = dinv[wid];
        float4 b = *(const float4*)(bias + (lane & 15) * 4);
        float4 o = make_float4(fmaxf(fmaf(acc[0], dv, b.x), 0.f),
                               fmaxf(fmaf(acc[1], dv, b.y), 0.f),
                               fmaxf(fmaf(acc[2], dv, b.z), 0.f),
                               fmaxf(fmaf(acc[3], dv, b.w), 0.f));
        *(float4*)((char*)out + (size_t)wid * 256u + coff * 2u) = o;
    }
}

// ---------------- launch ----------------

extern "C" void kernel_launch(void* const* d_in, const int* in_sizes, int n_in,
                              void* d_out, int out_size, void* d_ws, size_t ws_size,
                              hipStream_t stream) {
    const float* x      = (const float*)d_in[0];
    const float* W_enc  = (const float*)d_in[1];
    const float* b_enc  = (const float*)d_in[2];
    const float* W_conv = (const float*)d_in[3];
    const float* b_conv = (const float*)d_in[4];
    const float* W_dec  = (const float*)d_in[5];
    const float* b_dec  = (const float*)d_in[6];
    const int*   ei     = (const int*)d_in[7];

    const int N = N_NODES;
    const int E = N_EDGES;
    const int* src = ei;
    const int* dst = ei + E;

    size_t off = 0;
    auto carve = [&](size_t bytes) -> void* {
        void* p = (char*)d_ws + off;
        off = (off + bytes + 255) & ~(size_t)255;
        return p;
    };
    unsigned short* Xb      = (unsigned short*)carve((size_t)MPAD * 256 * 2);
    unsigned short* Hb      = (unsigned short*)carve((size_t)MPAD * 256 * 2);
    unsigned short* Wt_enc  = (unsigned short*)carve((size_t)256 * 256 * 2);
    unsigned short* Wt_conv = (unsigned short*)carve((size_t)256 * 256 * 2);
    unsigned short* Wt_dec  = (unsigned short*)carve((size_t)64 * 256 * 2);
    int*            scnt    = (int*)carve((size_t)N * sizeof(int));
    int*            dcnt    = (int*)carve((size_t)N * sizeof(int));
    float*          dinv    = (float*)carve((size_t)N * sizeof(float));
    int*            soff    = (int*)carve((size_t)(N + 1) * sizeof(int));
    int*            doff    = (int*)carve((size_t)(N + 1) * sizeof(int));
    int*            csr_src = (int*)carve((size_t)E * sizeof(int));
    int2*           tmp     = (int2*)carve((size_t)E * sizeof(int2));
    int*            blksum  = (int*)carve((size_t)NB_SCAN * sizeof(int));
    int*            blkpref = (int*)carve((size_t)NB_SCAN * sizeof(int));
    (void)ws_size;

    // --- prep ---
    k_cvt_x<<<MPAD / 4, 256, 0, stream>>>(x, Xb);
    k_prep_w<<<(256 * 256 + 255) / 256, 256, 0, stream>>>(W_enc, Wt_enc, 256);
    k_prep_w<<<(256 * 256 + 255) / 256, 256, 0, stream>>>(W_conv, Wt_conv, 256);
    k_prep_w<<<(256 * 64 + 255) / 256, 256, 0, stream>>>(W_dec, Wt_dec, 64);

    // --- CSR build: histograms, scans, double scatter (approx src-sorted per-dest lists) ---
    k_init<<<(N + 255) / 256, 256, 0, stream>>>(scnt, dcnt, N);
    k_hist<<<(E / 4 + 255) / 256, 256, 0, stream>>>(src, dst, scnt, dcnt, E);
    // scan src counts -> soff
    k_scan_blocks<<<NB_SCAN, 256, 0, stream>>>(scnt, blksum, N);
    k_scan_top<<<1, 512, 0, stream>>>(blksum, blkpref, soff, NB_SCAN, N);
    k_scan_final<<<NB_SCAN, 256, 0, stream>>>(scnt, blkpref, soff, nullptr, N);
    // scan dst counts -> doff (+dinv)
    k_scan_blocks<<<NB_SCAN, 256, 0, stream>>>(dcnt, blksum, N);
    k_scan_top<<<1, 512, 0, stream>>>(blksum, blkpref, doff, NB_SCAN, N);
    k_scan_final<<<NB_SCAN, 256, 0, stream>>>(dcnt, blkpref, doff, dinv, N);
    // scatter passes
    k_scatter1<<<(E + 255) / 256, 256, 0, stream>>>(src, dst, soff, scnt, tmp, E);
    k_scatter2<<<(E + 255) / 256, 256, 0, stream>>>(tmp, doff, dcnt, csr_src, E);

    dim3 gconv(MPAD / 128, 2);   // BN=128
    dim3 gdec(MPAD / 128, 1);    // BN=64
    const int agg_blocks = (N + 3) / 4;   // 4 waves/block, 1 node/wave

    // --- encoder ---
    k_mfma_gemm<128, true><<<gconv, 256, 0, stream>>>(Xb, Wt_enc, dinv, Hb, 256);
    k_agg256<<<agg_blocks, 256, 0, stream>>>(Hb, doff, csr_src, dinv, b_enc, Xb, N);
    // --- 4 conv layers ---
    for (int l = 0; l < 4; ++l) {
        k_mfma_gemm<128, true><<<gconv, 256, 0, stream>>>(Xb, Wt_conv, dinv, Hb, 256);
        k_agg256<<<agg_blocks, 256, 0, stream>>>(Hb, doff, csr_src, dinv, b_conv, Xb, N);
    }
    // --- decoder ---
    k_mfma_gemm<64, true><<<gdec, 256, 0, stream>>>(Xb, Wt_dec, dinv, Hb, 64);
    k_agg64<<<agg_blocks, 256, 0, stream>>>(Hb, doff, csr_src, dinv, b_dec,
                                            (float*)d_out, N);
}

// Round 12
// 1020.710 us; speedup vs baseline: 1.1771x; 1.1771x over previous
//
#include <hip/hip_runtime.h>

#define N_NODES 100000
#define N_EDGES 1600000
#define MPAD    100096   // 782 * 128
#define NB_SCAN ((N_NODES + 255) / 256)   // 391
#define NBX     (MPAD / 4)                // cvt_x blocks: 25024

using short8  = __attribute__((ext_vector_type(8))) short;
using ushort8 = __attribute__((ext_vector_type(8))) unsigned short;
using f32x4   = __attribute__((ext_vector_type(4))) float;

__device__ inline unsigned short f2bf(float f) {
    unsigned u = __float_as_uint(f);
    unsigned r = (u + 0x7fffu + ((u >> 16) & 1u)) >> 16;  // RNE
    return (unsigned short)r;
}
__device__ inline float bf2f(unsigned short h) {
    return __uint_as_float(((unsigned)h) << 16);
}

// ---------------- prep mega-kernel: cvt_x + W^T x3 + zero counters ----------------
// blocks [0,NBX): x->bf16; [NBX,NBX+256): Wenc^T; +256: Wconv^T; +64: Wdec^T; +NB_SCAN: zero cnt

__global__ __launch_bounds__(256) void k_prep(const float* __restrict__ x,
                                              const float* __restrict__ W_enc,
                                              const float* __restrict__ W_conv,
                                              const float* __restrict__ W_dec,
                                              unsigned short* __restrict__ xb,
                                              unsigned short* __restrict__ Wt_enc,
                                              unsigned short* __restrict__ Wt_conv,
                                              unsigned short* __restrict__ Wt_dec,
                                              int* __restrict__ cnt) {
    int b = blockIdx.x;
    if (b < NBX) {
        int i = b * 256 + threadIdx.x;          // one thread = 4 elems
        int row = i >> 6;
        ushort4 o;
        if (row < N_NODES) {
            float4 v = *(const float4*)(x + (size_t)i * 4);
            o.x = f2bf(v.x); o.y = f2bf(v.y); o.z = f2bf(v.z); o.w = f2bf(v.w);
        } else {
            o.x = o.y = o.z = o.w = 0;
        }
        *(ushort4*)(xb + (size_t)i * 4) = o;
        return;
    }
    b -= NBX;
    if (b < 256) {                              // Wenc [256][256] -> [N][K]
        int i = b * 256 + threadIdx.x;
        int r = i >> 8, c = i & 255;
        Wt_enc[(size_t)c * 256 + r] = f2bf(W_enc[i]);
        return;
    }
    b -= 256;
    if (b < 256) {
        int i = b * 256 + threadIdx.x;
        int r = i >> 8, c = i & 255;
        Wt_conv[(size_t)c * 256 + r] = f2bf(W_conv[i]);
        return;
    }
    b -= 256;
    if (b < 64) {                               // Wdec [256][64]
        int i = b * 256 + threadIdx.x;
        int r = i >> 6, c = i & 63;
        Wt_dec[(size_t)c * 256 + r] = f2bf(W_dec[i]);
        return;
    }
    b -= 64;
    {                                           // zero indeg counters
        int i = b * 256 + threadIdx.x;
        if (i < N_NODES) cnt[i] = 0;
    }
}

// ---------------- CSR build ----------------

__global__ __launch_bounds__(256) void k_indeg(const int* __restrict__ dst,
                                               int* __restrict__ indeg, int e) {
    int i = (blockIdx.x * blockDim.x + threadIdx.x) * 4;
    if (i < e) {
        int4 d = *(const int4*)(dst + i);
        atomicAdd(&indeg[d.x], 1);
        atomicAdd(&indeg[d.y], 1);
        atomicAdd(&indeg[d.z], 1);
        atomicAdd(&indeg[d.w], 1);
    }
}

__global__ __launch_bounds__(256) void k_scan_blocks(const int* __restrict__ cnt,
                                                     int* __restrict__ blksum, int n) {
    int i = blockIdx.x * 256 + threadIdx.x;
    int v = (i < n) ? cnt[i] : 0;
#pragma unroll
    for (int o = 32; o > 0; o >>= 1) v += __shfl_down(v, o, 64);
    __shared__ int ws[4];
    if ((threadIdx.x & 63) == 0) ws[threadIdx.x >> 6] = v;
    __syncthreads();
    if (threadIdx.x == 0) blksum[blockIdx.x] = ws[0] + ws[1] + ws[2] + ws[3];
}

__global__ __launch_bounds__(512) void k_scan_top(const int* __restrict__ blksum,
                                                  int* __restrict__ blkpref,
                                                  int* __restrict__ offsets, int nb, int n) {
    __shared__ int s[512];
    int t = threadIdx.x;
    int v = (t < nb) ? blksum[t] : 0;
    s[t] = v;
    __syncthreads();
    for (int o = 1; o < 512; o <<= 1) {
        int u = (t >= o) ? s[t - o] : 0;
        __syncthreads();
        s[t] += u;
        __syncthreads();
    }
    if (t < nb) blkpref[t] = (t == 0) ? 0 : s[t - 1];
    if (t == nb - 1) offsets[n] = s[t];
}

__global__ __launch_bounds__(256) void k_scan_final(const int* __restrict__ cnt,
                                                    const int* __restrict__ blkpref,
                                                    int* __restrict__ offsets,
                                                    float* __restrict__ dinv, int n) {
    __shared__ int s[256];
    int t = threadIdx.x;
    int i = blockIdx.x * 256 + t;
    int v = (i < n) ? cnt[i] : 0;
    s[t] = v;
    __syncthreads();
    for (int o = 1; o < 256; o <<= 1) {
        int u = (t >= o) ? s[t - o] : 0;
        __syncthreads();
        s[t] += u;
        __syncthreads();
    }
    if (i < n) {
        offsets[i] = blkpref[blockIdx.x] + s[t] - v;   // exclusive prefix
        dinv[i] = rsqrtf((float)(v + 1));              // +1 self-loop
    }
}

// scatter src into CSR slots; consumes indeg as countdown cursor; 4 edges/thread
__global__ __launch_bounds__(256) void k_scatter(const int* __restrict__ src,
                                                 const int* __restrict__ dst,
                                                 const int* __restrict__ offsets,
                                                 int* __restrict__ indeg,
                                                 int* __restrict__ csr_src, int e) {
    int i = (blockIdx.x * blockDim.x + threadIdx.x) * 4;
    if (i < e) {
        int4 s4 = *(const int4*)(src + i);
        int4 d4 = *(const int4*)(dst + i);
        int p;
        p = offsets[d4.x] + atomicSub(&indeg[d4.x], 1) - 1; csr_src[p] = s4.x;
        p = offsets[d4.y] + atomicSub(&indeg[d4.y], 1) - 1; csr_src[p] = s4.y;
        p = offsets[d4.z] + atomicSub(&indeg[d4.z], 1) - 1; csr_src[p] = s4.z;
        p = offsets[d4.w] + atomicSub(&indeg[d4.w], 1) - 1; csr_src[p] = s4.w;
    }
}

// ---------------- bf16 MFMA GEMM: C = dinv ⊙ (A @ Bt^T) ----------------

template <int BN>
__global__ __launch_bounds__(256) void k_mfma_gemm(const unsigned short* __restrict__ A,
                                                   const unsigned short* __restrict__ Bt,
                                                   const float* __restrict__ dinv,
                                                   unsigned short* __restrict__ C,
                                                   int Ntot) {
    constexpr int K = 256, BK = 64;
    constexpr int NFR = BN / 32;            // 16-col frags per wave
    __shared__ char ldsA[128 * 128];
    __shared__ char ldsB[BN * 128];
    const int tid  = threadIdx.x;
    const int lane = tid & 63;
    const int wid  = tid >> 6;
    const int wr   = wid >> 1, wc = wid & 1;
    const int row0 = blockIdx.x * 128;
    const int col0 = blockIdx.y * BN;
    const int l15  = lane & 15, lhi = lane >> 4;

    f32x4 acc[4][NFR];
#pragma unroll
    for (int m = 0; m < 4; ++m)
#pragma unroll
        for (int n = 0; n < NFR; ++n) acc[m][n] = {0.f, 0.f, 0.f, 0.f};

    for (int k0 = 0; k0 < K; k0 += BK) {
#pragma unroll
        for (int j = 0; j < 4; ++j) {
            int ci = j * 256 + tid;
            int r = ci >> 3;
            int cb = (ci & 7) ^ (r & 7);
            const char* src = (const char*)(A + (size_t)(row0 + r) * K + k0) + cb * 16;
            __builtin_amdgcn_global_load_lds((const __attribute__((address_space(1))) void*)src,
                                             (__attribute__((address_space(3))) void*)(ldsA + ci * 16),
                                             16, 0, 0);
        }
#pragma unroll
        for (int j = 0; j < BN / 32; ++j) {
            int ci = j * 256 + tid;
            int r = ci >> 3;
            int cb = (ci & 7) ^ (r & 7);
            const char* src = (const char*)(Bt + (size_t)(col0 + r) * K + k0) + cb * 16;
            __builtin_amdgcn_global_load_lds((const __attribute__((address_space(1))) void*)src,
                                             (__attribute__((address_space(3))) void*)(ldsB + ci * 16),
                                             16, 0, 0);
        }
        __syncthreads();
#pragma unroll
        for (int kk = 0; kk < 2; ++kk) {
            short8 af[4], bfr[NFR];
            int cb = kk * 4 + lhi;
#pragma unroll
            for (int m = 0; m < 4; ++m) {
                int r = wr * 64 + m * 16 + l15;
                af[m] = *(const short8*)(ldsA + r * 128 + ((cb ^ (r & 7)) << 4));
            }
#pragma unroll
            for (int n = 0; n < NFR; ++n) {
                int r = wc * (NFR * 16) + n * 16 + l15;
                bfr[n] = *(const short8*)(ldsB + r * 128 + ((cb ^ (r & 7)) << 4));
            }
#pragma unroll
            for (int m = 0; m < 4; ++m)
#pragma unroll
                for (int n = 0; n < NFR; ++n)
                    acc[m][n] = __builtin_amdgcn_mfma_f32_16x16x32_bf16(af[m], bfr[n],
                                                                        acc[m][n], 0, 0, 0);
        }
        __syncthreads();
    }
#pragma unroll
    for (int m = 0; m < 4; ++m) {
        int rbase = row0 + wr * 64 + m * 16 + lhi * 4;
        float sc[4];
#pragma unroll
        for (int q = 0; q < 4; ++q) {
            int grow = rbase + q;
            sc[q] = (grow < N_NODES) ? dinv[grow] : 0.f;
        }
#pragma unroll
        for (int n = 0; n < NFR; ++n) {
            int col = col0 + wc * (NFR * 16) + n * 16 + l15;
#pragma unroll
            for (int q = 0; q < 4; ++q)
                C[(size_t)(rbase + q) * Ntot + col] = f2bf(acc[m][n][q] * sc[q]);
        }
    }
}

// ---------------- aggregation F=256: out = relu(dinv[d]*(ΣH'[s] + H'[d]) + b) ----------------
// one wave per node; half-wave per edge (32 lanes x 16B); weightless edges (R7 proven).

__global__ __launch_bounds__(256) void k_agg256(const unsigned short* __restrict__ H,
                                                const int* __restrict__ offsets,
                                                const int* __restrict__ csr_src,
                                                const float* __restrict__ dinv,
                                                const float* __restrict__ bias,
                                                unsigned short* __restrict__ out, int n) {
    const int wid = __builtin_amdgcn_readfirstlane((blockIdx.x * blockDim.x + threadIdx.x) >> 6);
    if (wid >= n) return;
    const int lane = threadIdx.x & 63;
    const int half = lane >> 5;
    const unsigned coff = (unsigned)(lane & 31) * 16u;

    float acc[8] = {};
    const int beg = offsets[wid], end = offsets[wid + 1];
    int e = beg;

    for (; e + 7 < end; e += 8) {
        int sj[8];
#pragma unroll
        for (int j = 0; j < 8; ++j) sj[j] = csr_src[e + j];
        unsigned o0 = (unsigned)(half ? sj[1] : sj[0]) * 512u + coff;
        unsigned o1 = (unsigned)(half ? sj[3] : sj[2]) * 512u + coff;
        unsigned o2 = (unsigned)(half ? sj[5] : sj[4]) * 512u + coff;
        unsigned o3 = (unsigned)(half ? sj[7] : sj[6]) * 512u + coff;
        ushort8 v0 = *(const ushort8*)((const char*)H + o0);
        ushort8 v1 = *(const ushort8*)((const char*)H + o1);
        ushort8 v2 = *(const ushort8*)((const char*)H + o2);
        ushort8 v3 = *(const ushort8*)((const char*)H + o3);
#pragma unroll
        for (int j = 0; j < 8; ++j) acc[j] += bf2f(v0[j]);
#pragma unroll
        for (int j = 0; j < 8; ++j) acc[j] += bf2f(v1[j]);
#pragma unroll
        for (int j = 0; j < 8; ++j) acc[j] += bf2f(v2[j]);
#pragma unroll
        for (int j = 0; j < 8; ++j) acc[j] += bf2f(v3[j]);
    }
    for (; e + 1 < end; e += 2) {
        int s0 = csr_src[e], s1 = csr_src[e + 1];
        unsigned off = (unsigned)(half ? s1 : s0) * 512u + coff;
        ushort8 v = *(const ushort8*)((const char*)H + off);
#pragma unroll
        for (int j = 0; j < 8; ++j) acc[j] += bf2f(v[j]);
    }
    // virtual pair: [tail edge (if any), self-loop]
    {
        int has_tail = (e < end);
        int sA = has_tail ? csr_src[e] : wid;
        float wB = has_tail ? 1.f : 0.f;
        unsigned off = (unsigned)(half ? wid : sA) * 512u + coff;
        float w = half ? wB : 1.f;
        ushort8 v = *(const ushort8*)((const char*)H + off);
#pragma unroll
        for (int j = 0; j < 8; ++j) acc[j] = fmaf(bf2f(v[j]), w, acc[j]);
    }

#pragma unroll
    for (int j = 0; j < 8; ++j) acc[j] += __shfl_xor(acc[j], 32);

    if (half == 0) {
        float dv = dinv[wid];
        const float* bp = bias + (lane & 31) * 8;
        float4 b0 = *(const float4*)bp;
        float4 b1 = *(const float4*)(bp + 4);
        ushort8 o;
        o[0] = f2bf(fmaxf(fmaf(acc[0], dv, b0.x), 0.f));
        o[1] = f2bf(fmaxf(fmaf(acc[1], dv, b0.y), 0.f));
        o[2] = f2bf(fmaxf(fmaf(acc[2], dv, b0.z), 0.f));
        o[3] = f2bf(fmaxf(fmaf(acc[3], dv, b0.w), 0.f));
        o[4] = f2bf(fmaxf(fmaf(acc[4], dv, b1.x), 0.f));
        o[5] = f2bf(fmaxf(fmaf(acc[5], dv, b1.y), 0.f));
        o[6] = f2bf(fmaxf(fmaf(acc[6], dv, b1.z), 0.f));
        o[7] = f2bf(fmaxf(fmaf(acc[7], dv, b1.w), 0.f));
        *(ushort8*)((char*)out + (unsigned)wid * 512u + coff) = o;
    }
}

// ---------------- aggregation F=64 (decoder): f32 out ----------------

__global__ __launch_bounds__(256) void k_agg64(const unsigned short* __restrict__ H,
                                               const int* __restrict__ offsets,
                                               const int* __restrict__ csr_src,
                                               const float* __restrict__ dinv,
                                               const float* __restrict__ bias,
                                               float* __restrict__ out, int n) {
    const int wid = __builtin_amdgcn_readfirstlane((blockIdx.x * blockDim.x + threadIdx.x) >> 6);
    if (wid >= n) return;
    const int lane = threadIdx.x & 63;
    const int q = lane >> 4;
    const unsigned coff = (unsigned)(lane & 15) * 8u;

    float acc[4] = {};
    const int beg = offsets[wid], end = offsets[wid + 1];
    int e = beg;

    for (; e + 3 < end; e += 4) {
        int s0 = csr_src[e], s1 = csr_src[e + 1], s2 = csr_src[e + 2], s3 = csr_src[e + 3];
        int srow = s0;
        if (q == 1) srow = s1;
        else if (q == 2) srow = s2;
        else if (q == 3) srow = s3;
        ushort4 v = *(const ushort4*)((const char*)H + (unsigned)srow * 128u + coff);
        acc[0] += bf2f(v.x); acc[1] += bf2f(v.y);
        acc[2] += bf2f(v.z); acc[3] += bf2f(v.w);
    }
    {
        int r = end - e;
        int srow = wid; float wgt = 0.f;
        if (q < r) { srow = csr_src[e + q]; wgt = 1.f; }
        else if (q == r) { srow = wid; wgt = 1.f; }
        ushort4 v = *(const ushort4*)((const char*)H + (unsigned)srow * 128u + coff);
        acc[0] = fmaf(bf2f(v.x), wgt, acc[0]);
        acc[1] = fmaf(bf2f(v.y), wgt, acc[1]);
        acc[2] = fmaf(bf2f(v.z), wgt, acc[2]);
        acc[3] = fmaf(bf2f(v.w), wgt, acc[3]);
    }
#pragma unroll
    for (int j = 0; j < 4; ++j) {
        acc[j] += __shfl_xor(acc[j], 16);
        acc[j] += __shfl_xor(acc[j], 32);
    }
    if (q == 0) {
        float dv = dinv[wid];
        float4 b = *(const float4*)(bias + (lane & 15) * 4);
        float4 o = make_float4(fmaxf(fmaf(acc[0], dv, b.x), 0.f),
                               fmaxf(fmaf(acc[1], dv, b.y), 0.f),
                               fmaxf(fmaf(acc[2], dv, b.z), 0.f),
                               fmaxf(fmaf(acc[3], dv, b.w), 0.f));
        *(float4*)((char*)out + (size_t)wid * 256u + coff * 2u) = o;
    }
}

// ---------------- launch ----------------

extern "C" void kernel_launch(void* const* d_in, const int* in_sizes, int n_in,
                              void* d_out, int out_size, void* d_ws, size_t ws_size,
                              hipStream_t stream) {
    const float* x      = (const float*)d_in[0];
    const float* W_enc  = (const float*)d_in[1];
    const float* b_enc  = (const float*)d_in[2];
    const float* W_conv = (const float*)d_in[3];
    const float* b_conv = (const float*)d_in[4];
    const float* W_dec  = (const float*)d_in[5];
    const float* b_dec  = (const float*)d_in[6];
    const int*   ei     = (const int*)d_in[7];

    const int N = N_NODES;
    const int E = N_EDGES;
    const int* src = ei;
    const int* dst = ei + E;

    size_t off = 0;
    auto carve = [&](size_t bytes) -> void* {
        void* p = (char*)d_ws + off;
        off = (off + bytes + 255) & ~(size_t)255;
        return p;
    };
    unsigned short* Xb      = (unsigned short*)carve((size_t)MPAD * 256 * 2);
    unsigned short* Hb      = (unsigned short*)carve((size_t)MPAD * 256 * 2);
    unsigned short* Wt_enc  = (unsigned short*)carve((size_t)256 * 256 * 2);
    unsigned short* Wt_conv = (unsigned short*)carve((size_t)256 * 256 * 2);
    unsigned short* Wt_dec  = (unsigned short*)carve((size_t)64 * 256 * 2);
    int*            indeg   = (int*)carve((size_t)N * sizeof(int));
    float*          dinv    = (float*)carve((size_t)N * sizeof(float));
    int*            offsets = (int*)carve((size_t)(N + 1) * sizeof(int));
    int*            csr_src = (int*)carve((size_t)E * sizeof(int));
    int*            blksum  = (int*)carve((size_t)NB_SCAN * sizeof(int));
    int*            blkpref = (int*)carve((size_t)NB_SCAN * sizeof(int));
    (void)ws_size;

    // --- prep (fused: cvt_x, 3x W^T, zero counters) ---
    k_prep<<<NBX + 256 + 256 + 64 + NB_SCAN, 256, 0, stream>>>(
        x, W_enc, W_conv, W_dec, Xb, Wt_enc, Wt_conv, Wt_dec, indeg);
    // --- CSR build ---
    k_indeg<<<(E / 4 + 255) / 256, 256, 0, stream>>>(dst, indeg, E);
    k_scan_blocks<<<NB_SCAN, 256, 0, stream>>>(indeg, blksum, N);
    k_scan_top<<<1, 512, 0, stream>>>(blksum, blkpref, offsets, NB_SCAN, N);
    k_scan_final<<<NB_SCAN, 256, 0, stream>>>(indeg, blkpref, offsets, dinv, N);
    k_scatter<<<(E / 4 + 255) / 256, 256, 0, stream>>>(src, dst, offsets, indeg, csr_src, E);

    dim3 gconv(MPAD / 128, 2);   // BN=128
    dim3 gdec(MPAD / 128, 1);    // BN=64
    const int agg_blocks = (N + 3) / 4;   // 4 waves/block, 1 node/wave

    // --- encoder ---
    k_mfma_gemm<128><<<gconv, 256, 0, stream>>>(Xb, Wt_enc, dinv, Hb, 256);
    k_agg256<<<agg_blocks, 256, 0, stream>>>(Hb, offsets, csr_src, dinv, b_enc, Xb, N);
    // --- 4 conv layers ---
    for (int l = 0; l < 4; ++l) {
        k_mfma_gemm<128><<<gconv, 256, 0, stream>>>(Xb, Wt_conv, dinv, Hb, 256);
        k_agg256<<<agg_blocks, 256, 0, stream>>>(Hb, offsets, csr_src, dinv, b_conv, Xb, N);
    }
    // --- decoder ---
    k_mfma_gemm<64><<<gdec, 256, 0, stream>>>(Xb, Wt_dec, dinv, Hb, 64);
    k_agg64<<<agg_blocks, 256, 0, stream>>>(Hb, offsets, csr_src, dinv, b_dec,
                                            (float*)d_out, N);
}